// Round 6
// baseline (1291.910 us; speedup 1.0000x reference)
//
#include <hip/hip_runtime.h>
#include <hip/hip_bf16.h>

#define NN 100000
#define NE 800000
#define INC 64
#define HID 128
#define KC 9
#define NB 98  // ceil(NN/1024) scan blocks

// glob layout (floats): x_pool[1152] | out_adj[81] | ss[81] | den[1]  => 1315
#define G_XP 0
#define G_OA 1152
#define G_SS 1233
#define G_DEN 1314

__device__ __forceinline__ float atomAddG(float* p, float v) {
  return unsafeAtomicAdd(p, v);  // HW global_atomic_add_f32
}

// ---- CSR build: histogram -> 3-phase scan -> fill ----------------------

__global__ __launch_bounds__(256) void k_deg(const int* __restrict__ dst, int* __restrict__ degi) {
  int i = blockIdx.x * blockDim.x + threadIdx.x;
  int stride = gridDim.x * blockDim.x;
  for (; i < NE; i += stride) atomicAdd(&degi[dst[i]], 1);
}

__global__ __launch_bounds__(256) void k_bsum(const int* __restrict__ degi, int* __restrict__ bsum) {
  int t = threadIdx.x;
  int base = blockIdx.x * 1024 + t * 4;
  int d0 = 0, d1 = 0, d2 = 0, d3 = 0;
  if (base + 3 < NN) {
    int4 v = *(const int4*)(degi + base);
    d0 = v.x; d1 = v.y; d2 = v.z; d3 = v.w;
  } else {
    if (base < NN) d0 = degi[base];
    if (base + 1 < NN) d1 = degi[base + 1];
    if (base + 2 < NN) d2 = degi[base + 2];
  }
  int s = d0 + d1 + d2 + d3;
#pragma unroll
  for (int off = 32; off > 0; off >>= 1) s += __shfl_xor(s, off, 64);
  __shared__ int ws[4];
  if ((t & 63) == 0) ws[t >> 6] = s;
  __syncthreads();
  if (t == 0) bsum[blockIdx.x] = ws[0] + ws[1] + ws[2] + ws[3];
}

__global__ __launch_bounds__(128) void k_scanb(const int* __restrict__ bsum, int* __restrict__ boff) {
  __shared__ int sc[128];
  int t = threadIdx.x;
  int v = (t < NB) ? bsum[t] : 0;
  sc[t] = v;
  __syncthreads();
  for (int off = 1; off < 128; off <<= 1) {
    int u = (t >= off) ? sc[t - off] : 0;
    __syncthreads();
    sc[t] += u;
    __syncthreads();
  }
  if (t < NB) boff[t] = sc[t] - v;  // exclusive
}

__global__ __launch_bounds__(256) void k_write(const int* __restrict__ degi, const int* __restrict__ boff,
                                               int* __restrict__ rowptr, int* __restrict__ cursor,
                                               float* __restrict__ dinv) {
  int t = threadIdx.x;
  int base = blockIdx.x * 1024 + t * 4;
  int d0 = 0, d1 = 0, d2 = 0, d3 = 0;
  bool full = (base + 3 < NN);
  if (full) {
    int4 v = *(const int4*)(degi + base);
    d0 = v.x; d1 = v.y; d2 = v.z; d3 = v.w;
  } else {
    if (base < NN) d0 = degi[base];
    if (base + 1 < NN) d1 = degi[base + 1];
    if (base + 2 < NN) d2 = degi[base + 2];
  }
  int tsum = d0 + d1 + d2 + d3;
  __shared__ int sc[256];
  sc[t] = tsum;
  __syncthreads();
  for (int off = 1; off < 256; off <<= 1) {
    int u = (t >= off) ? sc[t - off] : 0;
    __syncthreads();
    sc[t] += u;
    __syncthreads();
  }
  int ex = sc[t] - tsum + boff[blockIdx.x];
  int r0 = ex, r1 = ex + d0, r2 = r1 + d1, r3 = r2 + d2;
  if (full) {
    int4 rv = make_int4(r0, r1, r2, r3);
    *(int4*)(rowptr + base) = rv;
    *(int4*)(cursor + base) = rv;
    float4 dv = make_float4(rsqrtf((float)d0 + 1.f), rsqrtf((float)d1 + 1.f),
                            rsqrtf((float)d2 + 1.f), rsqrtf((float)d3 + 1.f));
    *(float4*)(dinv + base) = dv;
  } else {
    if (base < NN) { rowptr[base] = r0; cursor[base] = r0; dinv[base] = rsqrtf((float)d0 + 1.f); }
    if (base + 1 < NN) { rowptr[base + 1] = r1; cursor[base + 1] = r1; dinv[base + 1] = rsqrtf((float)d1 + 1.f); }
    if (base + 2 < NN) { rowptr[base + 2] = r2; cursor[base + 2] = r2; dinv[base + 2] = rsqrtf((float)d2 + 1.f); }
  }
}

__global__ __launch_bounds__(256) void k_fill(const int* __restrict__ src, const int* __restrict__ dst,
                                              int* __restrict__ cursor, int* __restrict__ csr) {
  int i = blockIdx.x * blockDim.x + threadIdx.x;
  int stride = gridDim.x * blockDim.x;
  for (; i < NE; i += stride) {
    int p = atomicAdd(&cursor[dst[i]], 1);
    csr[p] = src[i];
  }
}

// ---- pure gather: agg = A_hat x  (4 nodes/wave, 16 lanes/node, x4 unroll)

__global__ __launch_bounds__(256) void k_gather(const int* __restrict__ rowptr, const int* __restrict__ degi,
                                                const int* __restrict__ csr, const float* __restrict__ x,
                                                const float* __restrict__ dinv, float* __restrict__ agg) {
  int t = threadIdx.x;
  int wave = t >> 6, lane = t & 63;
  int gw = blockIdx.x * 4 + wave;
  int ng = lane >> 4, c4 = lane & 15;
  int node = gw * 4 + ng;
  if (node >= NN) return;

  float dv = dinv[node];
  int base = rowptr[node];
  int cnt = degi[node];

  float4 xs = ((const float4*)(x + (size_t)node * INC))[c4];
  float dv2 = dv * dv;
  float4 acc;
  acc.x = dv2 * xs.x; acc.y = dv2 * xs.y; acc.z = dv2 * xs.z; acc.w = dv2 * xs.w;

  int j = 0;
  for (; j + 3 < cnt; j += 4) {
    int s0 = csr[base + j], s1 = csr[base + j + 1], s2 = csr[base + j + 2], s3 = csr[base + j + 3];
    float w0 = dinv[s0] * dv, w1 = dinv[s1] * dv, w2 = dinv[s2] * dv, w3 = dinv[s3] * dv;
    float4 r0 = ((const float4*)(x + (size_t)s0 * INC))[c4];
    float4 r1 = ((const float4*)(x + (size_t)s1 * INC))[c4];
    float4 r2 = ((const float4*)(x + (size_t)s2 * INC))[c4];
    float4 r3 = ((const float4*)(x + (size_t)s3 * INC))[c4];
    acc.x = fmaf(w0, r0.x, acc.x); acc.y = fmaf(w0, r0.y, acc.y);
    acc.z = fmaf(w0, r0.z, acc.z); acc.w = fmaf(w0, r0.w, acc.w);
    acc.x = fmaf(w1, r1.x, acc.x); acc.y = fmaf(w1, r1.y, acc.y);
    acc.z = fmaf(w1, r1.z, acc.z); acc.w = fmaf(w1, r1.w, acc.w);
    acc.x = fmaf(w2, r2.x, acc.x); acc.y = fmaf(w2, r2.y, acc.y);
    acc.z = fmaf(w2, r2.z, acc.z); acc.w = fmaf(w2, r2.w, acc.w);
    acc.x = fmaf(w3, r3.x, acc.x); acc.y = fmaf(w3, r3.y, acc.y);
    acc.z = fmaf(w3, r3.z, acc.z); acc.w = fmaf(w3, r3.w, acc.w);
  }
  for (; j < cnt; ++j) {
    int si = csr[base + j];
    float w = dinv[si] * dv;
    float4 r = ((const float4*)(x + (size_t)si * INC))[c4];
    acc.x = fmaf(w, r.x, acc.x); acc.y = fmaf(w, r.y, acc.y);
    acc.z = fmaf(w, r.z, acc.z); acc.w = fmaf(w, r.w, acc.w);
  }
  ((float4*)(agg + (size_t)node * INC))[c4] = acc;
}

// ---- MLP A: node-per-thread, broadcast-only LDS. h=relu(agg@W1+b1) -> h_glob,
//      logits=h@Wp+bp, softmax -> s_out, s_pad. Zero shuffles, zero bank conflicts.

__global__ __launch_bounds__(256, 4) void k_mlpA(const float* __restrict__ agg,
                                                 const float* __restrict__ W1, const float* __restrict__ b1,
                                                 const float* __restrict__ Wp, const float* __restrict__ bp,
                                                 float* __restrict__ s_out, float* __restrict__ s_pad,
                                                 float* __restrict__ h_glob) {
  __shared__ float W1s[INC * HID];   // 32 KB, row-major [k][c]
  __shared__ float Wps[HID * 12];    // 6 KB, rows padded to 12 (16B aligned)

  int t = threadIdx.x;
  for (int i = t; i < (INC * HID) / 4; i += 256) ((float4*)W1s)[i] = ((const float4*)W1)[i];
  for (int i = t; i < HID * KC; i += 256) { int c = i / KC, q = i - c * KC; Wps[c * 12 + q] = Wp[i]; }
  __syncthreads();

  int node = blockIdx.x * 256 + t;
  if (node >= NN) return;
  const float4* arow = (const float4*)(agg + (size_t)node * INC);

  float logit[KC];
#pragma unroll
  for (int q = 0; q < KC; ++q) logit[q] = bp[q];  // uniform -> scalar path

  for (int half = 0; half < 2; ++half) {
    float h[64];
#pragma unroll
    for (int i = 0; i < 64; ++i) h[i] = b1[half * 64 + i];

#pragma unroll 1
    for (int k4 = 0; k4 < 16; ++k4) {
      float4 av = arow[k4];
#pragma unroll
      for (int kk = 0; kk < 4; ++kk) {
        float ak = (kk == 0) ? av.x : (kk == 1) ? av.y : (kk == 2) ? av.z : av.w;
        const float4* wrow = (const float4*)&W1s[(k4 * 4 + kk) * HID + half * 64];
#pragma unroll
        for (int i = 0; i < 16; ++i) {
          float4 w = wrow[i];  // wave-uniform broadcast read
          h[4 * i + 0] = fmaf(ak, w.x, h[4 * i + 0]);
          h[4 * i + 1] = fmaf(ak, w.y, h[4 * i + 1]);
          h[4 * i + 2] = fmaf(ak, w.z, h[4 * i + 2]);
          h[4 * i + 3] = fmaf(ak, w.w, h[4 * i + 3]);
        }
      }
    }

    // relu + logit accumulation + store h
#pragma unroll 4
    for (int i = 0; i < 64; ++i) {
      float hr = fmaxf(h[i], 0.f);
      h[i] = hr;
      const float4* wp = (const float4*)&Wps[(half * 64 + i) * 12];
      float4 w0 = wp[0], w1 = wp[1], w2 = wp[2];  // broadcast
      logit[0] = fmaf(hr, w0.x, logit[0]);
      logit[1] = fmaf(hr, w0.y, logit[1]);
      logit[2] = fmaf(hr, w0.z, logit[2]);
      logit[3] = fmaf(hr, w0.w, logit[3]);
      logit[4] = fmaf(hr, w1.x, logit[4]);
      logit[5] = fmaf(hr, w1.y, logit[5]);
      logit[6] = fmaf(hr, w1.z, logit[6]);
      logit[7] = fmaf(hr, w1.w, logit[7]);
      logit[8] = fmaf(hr, w2.x, logit[8]);
    }
    float4* hout = (float4*)(h_glob + (size_t)node * HID + half * 64);
#pragma unroll
    for (int i = 0; i < 16; ++i) hout[i] = make_float4(h[4 * i], h[4 * i + 1], h[4 * i + 2], h[4 * i + 3]);
  }

  // softmax (lane-local)
  float m = logit[0];
#pragma unroll
  for (int q = 1; q < KC; ++q) m = fmaxf(m, logit[q]);
  float Z = 0.f;
#pragma unroll
  for (int q = 0; q < KC; ++q) { logit[q] = __expf(logit[q] - m); Z += logit[q]; }
  float inv = 1.0f / Z;
#pragma unroll
  for (int q = 0; q < KC; ++q) logit[q] *= inv;

  float* so = s_out + (size_t)node * KC;
#pragma unroll
  for (int q = 0; q < KC; ++q) so[q] = logit[q];
  float4* sp = (float4*)(s_pad + (size_t)node * 12);
  sp[0] = make_float4(logit[0], logit[1], logit[2], logit[3]);
  sp[1] = make_float4(logit[4], logit[5], logit[6], logit[7]);
  sp[2] = make_float4(logit[8], 0.f, 0.f, 0.f);
}

// ---- pool B: column-ownership reductions. x_pool = S^T H, ss = S^T S, den.

__global__ __launch_bounds__(256) void k_poolB(const float* __restrict__ h_glob,
                                               const float* __restrict__ s_pad,
                                               const int* __restrict__ degi,
                                               float* __restrict__ glob) {
  int t = threadIdx.x;
  int wave = t >> 6, lane = t & 63;
  int gw = blockIdx.x * 4 + wave;
  int nw = gridDim.x * 4;
  const int c0 = 2 * lane;

  float pool0[KC], pool1[KC], ssr[KC];
  float den_acc = 0.f;
#pragma unroll
  for (int q = 0; q < KC; ++q) { pool0[q] = 0.f; pool1[q] = 0.f; ssr[q] = 0.f; }

  for (int node0 = gw; node0 < NN; node0 += nw) {
    int node = __builtin_amdgcn_readfirstlane(node0);  // force uniform -> scalar loads
    float2 hv = *(const float2*)&h_glob[(size_t)node * HID + c0];  // coalesced 512B
    const float* srow = s_pad + (size_t)node * 12;
    float4 s0 = *(const float4*)srow;       // uniform -> s_load
    float4 s1 = *(const float4*)(srow + 4);
    float s8 = srow[8];
    float sb[KC] = {s0.x, s0.y, s0.z, s0.w, s1.x, s1.y, s1.z, s1.w, s8};
    float sq = (lane < KC) ? srow[lane] : 0.f;  // per-lane
    float dg = (float)degi[node];               // uniform

#pragma unroll
    for (int q = 0; q < KC; ++q) {
      pool0[q] = fmaf(sb[q], hv.x, pool0[q]);
      pool1[q] = fmaf(sb[q], hv.y, pool1[q]);
    }
    if (lane < KC) {
#pragma unroll
      for (int q = 0; q < KC; ++q) ssr[q] = fmaf(sq, sb[q], ssr[q]);
      den_acc = fmaf(dg * sq, sq, den_acc);
    }
  }

  __shared__ float pool_sh[KC * HID + 82];
  float* ss_sh = pool_sh + KC * HID;
  float* den_sh = ss_sh + 81;
  for (int i = t; i < KC * HID + 82; i += 256) pool_sh[i] = 0.f;
  __syncthreads();

#pragma unroll
  for (int q = 0; q < KC; ++q) {
    atomicAdd(&pool_sh[q * HID + c0], pool0[q]);
    atomicAdd(&pool_sh[q * HID + c0 + 1], pool1[q]);
  }
  if (lane < KC) {
#pragma unroll
    for (int q = 0; q < KC; ++q) atomicAdd(&ss_sh[lane * KC + q], ssr[q]);
    atomicAdd(den_sh, den_acc);
  }
  __syncthreads();

  for (int i = t; i < KC * HID; i += 256) atomAddG(&glob[G_XP + i], pool_sh[i]);
  if (t < KC * KC) atomAddG(&glob[G_SS + t], ss_sh[t]);
  if (t == 0) atomAddG(&glob[G_DEN], *den_sh);
}

// ---- out_adj via CSR: g[dst] = sum_{src in N(dst)} s[src]; OA = sum g(x)s[dst]

__global__ __launch_bounds__(256) void k_adj(const int* __restrict__ rowptr, const int* __restrict__ degi,
                                             const int* __restrict__ csr, const float* __restrict__ s_pad,
                                             float* __restrict__ oa_g) {
  int t = threadIdx.x;
  int tid = blockIdx.x * blockDim.x + t;
  int stride = gridDim.x * blockDim.x;

  float acc[81];
#pragma unroll
  for (int i = 0; i < 81; ++i) acc[i] = 0.f;

  for (int node = tid; node < NN; node += stride) {
    int base = rowptr[node];
    int cnt = degi[node];
    float4 g0 = make_float4(0.f, 0.f, 0.f, 0.f);
    float4 g1 = g0;
    float g8 = 0.f;
    int j = 0;
    for (; j + 1 < cnt; j += 2) {
      int s0 = csr[base + j], s1 = csr[base + j + 1];
      const float4* p0 = (const float4*)(s_pad + (size_t)s0 * 12);
      const float4* p1 = (const float4*)(s_pad + (size_t)s1 * 12);
      float4 a0 = p0[0], b0 = p0[1], c0 = p0[2];
      float4 a1 = p1[0], b1 = p1[1], c1 = p1[2];
      g0.x += a0.x + a1.x; g0.y += a0.y + a1.y; g0.z += a0.z + a1.z; g0.w += a0.w + a1.w;
      g1.x += b0.x + b1.x; g1.y += b0.y + b1.y; g1.z += b0.z + b1.z; g1.w += b0.w + b1.w;
      g8 += c0.x + c1.x;
    }
    if (j < cnt) {
      int s0 = csr[base + j];
      const float4* p0 = (const float4*)(s_pad + (size_t)s0 * 12);
      float4 a0 = p0[0], b0 = p0[1], c0 = p0[2];
      g0.x += a0.x; g0.y += a0.y; g0.z += a0.z; g0.w += a0.w;
      g1.x += b0.x; g1.y += b0.y; g1.z += b0.z; g1.w += b0.w;
      g8 += c0.x;
    }
    const float4* sn = (const float4*)(s_pad + (size_t)node * 12);
    float4 d0 = sn[0], d1 = sn[1], d2 = sn[2];
    float gg[9] = {g0.x, g0.y, g0.z, g0.w, g1.x, g1.y, g1.z, g1.w, g8};
    float sd[9] = {d0.x, d0.y, d0.z, d0.w, d1.x, d1.y, d1.z, d1.w, d2.x};
#pragma unroll
    for (int i = 0; i < 9; ++i)
#pragma unroll
      for (int jj = 0; jj < 9; ++jj) acc[i * 9 + jj] = fmaf(gg[i], sd[jj], acc[i * 9 + jj]);
  }

  __shared__ float wsum[4][81];
#pragma unroll
  for (int i = 0; i < 81; ++i) {
#pragma unroll
    for (int off = 32; off > 0; off >>= 1) acc[i] += __shfl_xor(acc[i], off, 64);
  }
  int wave = t >> 6, lane = t & 63;
  if (lane == 0) {
#pragma unroll
    for (int i = 0; i < 81; ++i) wsum[wave][i] = acc[i];
  }
  __syncthreads();
  if (t < 81) atomAddG(&oa_g[t], wsum[0][t] + wsum[1][t] + wsum[2][t] + wsum[3][t]);
}

// ---- epilogue ----------------------------------------------------------

__global__ __launch_bounds__(128) void k_final(const float* __restrict__ glob, float* __restrict__ out) {
  const float* xp = glob + G_XP;
  const float* oa = glob + G_OA;
  const float* ssm = glob + G_SS;
  const float* den = glob + G_DEN;
  int t = threadIdx.x;
  __shared__ float red[128];

  for (int k = 0; k < 9; ++k) {
    float v = xp[k * 128 + t];
    red[t] = v;
    __syncthreads();
    for (int s2 = 64; s2 > 0; s2 >>= 1) {
      if (t < s2) red[t] = fmaxf(red[t], red[t + s2]);
      __syncthreads();
    }
    float m = red[0];
    __syncthreads();
    red[t] = expf(v - m);
    __syncthreads();
    for (int s2 = 64; s2 > 0; s2 >>= 1) {
      if (t < s2) red[t] += red[t + s2];
      __syncthreads();
    }
    float lz = logf(red[0]) + m;
    __syncthreads();
    out[k * 128 + t] = v - lz;
  }

  if (t == 0) {
    float num = 0.f;
    for (int q = 0; q < 9; ++q) num += oa[q * 9 + q];
    out[1152] = -(num / (den[0] + 1e-15f));

    float fn = 0.f;
    for (int i = 0; i < 81; ++i) fn += ssm[i] * ssm[i];
    float rfn = 1.0f / sqrtf(fn);
    float osum = 0.f;
    for (int i = 0; i < 9; ++i)
      for (int j = 0; j < 9; ++j) {
        float v = ssm[i * 9 + j] * rfn - ((i == j) ? (1.0f / 3.0f) : 0.f);
        osum += v * v;
      }
    out[1153] = sqrtf(osum);
  }

  __shared__ float dsh[9];
  if (t < 9) {
    float d = 0.f;
    for (int j = 0; j < 9; ++j)
      if (j != t) d += oa[t * 9 + j];
    dsh[t] = 1.0f / sqrtf(d + 1e-15f);
  }
  __syncthreads();
  if (t < 81) {
    int i = t / 9, j = t % 9;
    out[901154 + t] = (i == j) ? 0.f : dsh[i] * oa[t] * dsh[j];
  }
}

extern "C" void kernel_launch(void* const* d_in, const int* in_sizes, int n_in,
                              void* d_out, int out_size, void* d_ws, size_t ws_size,
                              hipStream_t stream) {
  const float* x = (const float*)d_in[0];
  const int* ei = (const int*)d_in[1];
  const float* W1 = (const float*)d_in[3];
  const float* b1 = (const float*)d_in[4];
  const float* Wp = (const float*)d_in[5];
  const float* bp = (const float*)d_in[6];
  float* out = (float*)d_out;

  // ws: deg_i[NN] | glob[1315] | rowptr[NN] | cursor[NN] | csr[NE] | dinv[NN] |
  //     s_pad[NN*12] | bsum[NB] | boff[NB] | agg[NN*64] | h_glob[NN*128]
  int* deg_i = (int*)d_ws;
  float* glob = (float*)d_ws + NN;
  int* rowptr = (int*)d_ws + NN + 1315;
  int* cursor = rowptr + NN;
  int* csr = cursor + NN;
  float* dinv = (float*)(csr + NE);
  float* s_pad = dinv + NN;
  int* bsum = (int*)(s_pad + (size_t)NN * 12);
  int* boff = bsum + NB;
  float* agg = (float*)(boff + NB);
  float* h_glob = agg + (size_t)NN * INC;

  hipMemsetAsync(d_ws, 0, (size_t)(NN + 1315) * sizeof(float), stream);

  const int* src = ei;
  const int* dst = ei + NE;

  hipLaunchKernelGGL(k_deg, dim3(1024), dim3(256), 0, stream, dst, deg_i);
  hipLaunchKernelGGL(k_bsum, dim3(NB), dim3(256), 0, stream, deg_i, bsum);
  hipLaunchKernelGGL(k_scanb, dim3(1), dim3(128), 0, stream, bsum, boff);
  hipLaunchKernelGGL(k_write, dim3(NB), dim3(256), 0, stream, deg_i, boff, rowptr, cursor, dinv);
  hipLaunchKernelGGL(k_fill, dim3(1024), dim3(256), 0, stream, src, dst, cursor, csr);
  hipLaunchKernelGGL(k_gather, dim3(6250), dim3(256), 0, stream, rowptr, deg_i, csr, x, dinv, agg);
  hipLaunchKernelGGL(k_mlpA, dim3((NN + 255) / 256), dim3(256), 0, stream, agg,
                     W1, b1, Wp, bp, out + 1154, s_pad, h_glob);
  hipLaunchKernelGGL(k_poolB, dim3(512), dim3(256), 0, stream, h_glob, s_pad, deg_i, glob);
  hipLaunchKernelGGL(k_adj, dim3(512), dim3(256), 0, stream, rowptr, deg_i, csr, s_pad, glob + G_OA);
  hipLaunchKernelGGL(k_final, dim3(1), dim3(128), 0, stream, glob, out);
}

// Round 7
// 346.871 us; speedup vs baseline: 3.7245x; 3.7245x over previous
//
#include <hip/hip_runtime.h>
#include <hip/hip_bf16.h>

#define NN 100000
#define NE 800000
#define INC 64
#define HID 128
#define KC 9
#define NB 98  // ceil(NN/1024) scan blocks

// glob layout (floats): x_pool[1152] | out_adj[81] | ss[81] | den[1]  => 1315
#define G_XP 0
#define G_OA 1152
#define G_SS 1233
#define G_DEN 1314

__device__ __forceinline__ float atomAddG(float* p, float v) {
  return unsafeAtomicAdd(p, v);  // HW global_atomic_add_f32
}

// ---- CSR build: histogram -> 3-phase scan -> fill ----------------------

__global__ __launch_bounds__(256) void k_deg(const int* __restrict__ dst, int* __restrict__ degi) {
  int i = blockIdx.x * blockDim.x + threadIdx.x;
  int stride = gridDim.x * blockDim.x;
  for (; i < NE; i += stride) atomicAdd(&degi[dst[i]], 1);
}

__global__ __launch_bounds__(256) void k_bsum(const int* __restrict__ degi, int* __restrict__ bsum) {
  int t = threadIdx.x;
  int base = blockIdx.x * 1024 + t * 4;
  int d0 = 0, d1 = 0, d2 = 0, d3 = 0;
  if (base + 3 < NN) {
    int4 v = *(const int4*)(degi + base);
    d0 = v.x; d1 = v.y; d2 = v.z; d3 = v.w;
  } else {
    if (base < NN) d0 = degi[base];
    if (base + 1 < NN) d1 = degi[base + 1];
    if (base + 2 < NN) d2 = degi[base + 2];
  }
  int s = d0 + d1 + d2 + d3;
#pragma unroll
  for (int off = 32; off > 0; off >>= 1) s += __shfl_xor(s, off, 64);
  __shared__ int ws[4];
  if ((t & 63) == 0) ws[t >> 6] = s;
  __syncthreads();
  if (t == 0) bsum[blockIdx.x] = ws[0] + ws[1] + ws[2] + ws[3];
}

__global__ __launch_bounds__(128) void k_scanb(const int* __restrict__ bsum, int* __restrict__ boff) {
  __shared__ int sc[128];
  int t = threadIdx.x;
  int v = (t < NB) ? bsum[t] : 0;
  sc[t] = v;
  __syncthreads();
  for (int off = 1; off < 128; off <<= 1) {
    int u = (t >= off) ? sc[t - off] : 0;
    __syncthreads();
    sc[t] += u;
    __syncthreads();
  }
  if (t < NB) boff[t] = sc[t] - v;  // exclusive
}

__global__ __launch_bounds__(256) void k_write(const int* __restrict__ degi, const int* __restrict__ boff,
                                               int* __restrict__ rowptr, int* __restrict__ cursor,
                                               float* __restrict__ dinv) {
  int t = threadIdx.x;
  int base = blockIdx.x * 1024 + t * 4;
  int d0 = 0, d1 = 0, d2 = 0, d3 = 0;
  bool full = (base + 3 < NN);
  if (full) {
    int4 v = *(const int4*)(degi + base);
    d0 = v.x; d1 = v.y; d2 = v.z; d3 = v.w;
  } else {
    if (base < NN) d0 = degi[base];
    if (base + 1 < NN) d1 = degi[base + 1];
    if (base + 2 < NN) d2 = degi[base + 2];
  }
  int tsum = d0 + d1 + d2 + d3;
  __shared__ int sc[256];
  sc[t] = tsum;
  __syncthreads();
  for (int off = 1; off < 256; off <<= 1) {
    int u = (t >= off) ? sc[t - off] : 0;
    __syncthreads();
    sc[t] += u;
    __syncthreads();
  }
  int ex = sc[t] - tsum + boff[blockIdx.x];
  int r0 = ex, r1 = ex + d0, r2 = r1 + d1, r3 = r2 + d2;
  if (full) {
    int4 rv = make_int4(r0, r1, r2, r3);
    *(int4*)(rowptr + base) = rv;
    *(int4*)(cursor + base) = rv;
    float4 dv = make_float4(rsqrtf((float)d0 + 1.f), rsqrtf((float)d1 + 1.f),
                            rsqrtf((float)d2 + 1.f), rsqrtf((float)d3 + 1.f));
    *(float4*)(dinv + base) = dv;
  } else {
    if (base < NN) { rowptr[base] = r0; cursor[base] = r0; dinv[base] = rsqrtf((float)d0 + 1.f); }
    if (base + 1 < NN) { rowptr[base + 1] = r1; cursor[base + 1] = r1; dinv[base + 1] = rsqrtf((float)d1 + 1.f); }
    if (base + 2 < NN) { rowptr[base + 2] = r2; cursor[base + 2] = r2; dinv[base + 2] = rsqrtf((float)d2 + 1.f); }
  }
}

__global__ __launch_bounds__(256) void k_fill(const int* __restrict__ src, const int* __restrict__ dst,
                                              int* __restrict__ cursor, int* __restrict__ csr) {
  int i = blockIdx.x * blockDim.x + threadIdx.x;
  int stride = gridDim.x * blockDim.x;
  for (; i < NE; i += stride) {
    int p = atomicAdd(&cursor[dst[i]], 1);
    csr[p] = src[i];
  }
}

// ---- pure gather: agg = A_hat x  (4 nodes/wave, 16 lanes/node, x4 unroll)

__global__ __launch_bounds__(256) void k_gather(const int* __restrict__ rowptr, const int* __restrict__ degi,
                                                const int* __restrict__ csr, const float* __restrict__ x,
                                                const float* __restrict__ dinv, float* __restrict__ agg) {
  int t = threadIdx.x;
  int wave = t >> 6, lane = t & 63;
  int gw = blockIdx.x * 4 + wave;
  int ng = lane >> 4, c4 = lane & 15;
  int node = gw * 4 + ng;
  if (node >= NN) return;

  float dv = dinv[node];
  int base = rowptr[node];
  int cnt = degi[node];

  float4 xs = ((const float4*)(x + (size_t)node * INC))[c4];
  float dv2 = dv * dv;
  float4 acc;
  acc.x = dv2 * xs.x; acc.y = dv2 * xs.y; acc.z = dv2 * xs.z; acc.w = dv2 * xs.w;

  int j = 0;
  for (; j + 3 < cnt; j += 4) {
    int s0 = csr[base + j], s1 = csr[base + j + 1], s2 = csr[base + j + 2], s3 = csr[base + j + 3];
    float w0 = dinv[s0] * dv, w1 = dinv[s1] * dv, w2 = dinv[s2] * dv, w3 = dinv[s3] * dv;
    float4 r0 = ((const float4*)(x + (size_t)s0 * INC))[c4];
    float4 r1 = ((const float4*)(x + (size_t)s1 * INC))[c4];
    float4 r2 = ((const float4*)(x + (size_t)s2 * INC))[c4];
    float4 r3 = ((const float4*)(x + (size_t)s3 * INC))[c4];
    acc.x = fmaf(w0, r0.x, acc.x); acc.y = fmaf(w0, r0.y, acc.y);
    acc.z = fmaf(w0, r0.z, acc.z); acc.w = fmaf(w0, r0.w, acc.w);
    acc.x = fmaf(w1, r1.x, acc.x); acc.y = fmaf(w1, r1.y, acc.y);
    acc.z = fmaf(w1, r1.z, acc.z); acc.w = fmaf(w1, r1.w, acc.w);
    acc.x = fmaf(w2, r2.x, acc.x); acc.y = fmaf(w2, r2.y, acc.y);
    acc.z = fmaf(w2, r2.z, acc.z); acc.w = fmaf(w2, r2.w, acc.w);
    acc.x = fmaf(w3, r3.x, acc.x); acc.y = fmaf(w3, r3.y, acc.y);
    acc.z = fmaf(w3, r3.z, acc.z); acc.w = fmaf(w3, r3.w, acc.w);
  }
  for (; j < cnt; ++j) {
    int si = csr[base + j];
    float w = dinv[si] * dv;
    float4 r = ((const float4*)(x + (size_t)si * INC))[c4];
    acc.x = fmaf(w, r.x, acc.x); acc.y = fmaf(w, r.y, acc.y);
    acc.z = fmaf(w, r.z, acc.z); acc.w = fmaf(w, r.w, acc.w);
  }
  ((float4*)(agg + (size_t)node * INC))[c4] = acc;
}

// ---- MLP A: node-per-thread, broadcast-only LDS, chunked h (no scratch).
// a[64] in regs (const-indexed), h in 8 chunks of 16, all loops fully unrolled.

__global__ __launch_bounds__(256, 2) void k_mlpA(const float* __restrict__ agg,
                                                 const float* __restrict__ W1, const float* __restrict__ b1,
                                                 const float* __restrict__ Wp, const float* __restrict__ bp,
                                                 float* __restrict__ s_out, float* __restrict__ s_pad,
                                                 float* __restrict__ h_glob) {
  __shared__ float W1s[INC * HID];   // 32 KB, row-major [k][c]
  __shared__ float Wps[HID * 12];    // 6 KB, rows padded to 12
  __shared__ float b1s[HID];

  int t = threadIdx.x;
  for (int i = t; i < (INC * HID) / 4; i += 256) ((float4*)W1s)[i] = ((const float4*)W1)[i];
  for (int i = t; i < HID * KC; i += 256) { int c = i / KC, q = i - c * KC; Wps[c * 12 + q] = Wp[i]; }
  if (t < HID) b1s[t] = b1[t];
  __syncthreads();

  int node = blockIdx.x * 256 + t;
  if (node >= NN) return;

  // load own agg row into registers (constant indices -> full promotion)
  float a[INC];
  {
    const float4* arow = (const float4*)(agg + (size_t)node * INC);
#pragma unroll
    for (int i = 0; i < 16; ++i) {
      float4 v = arow[i];
      a[4 * i + 0] = v.x; a[4 * i + 1] = v.y; a[4 * i + 2] = v.z; a[4 * i + 3] = v.w;
    }
  }

  float logit[KC];
#pragma unroll
  for (int q = 0; q < KC; ++q) logit[q] = bp[q];  // uniform -> scalar load

  float4* hout = (float4*)(h_glob + (size_t)node * HID);

#pragma unroll 1
  for (int ch = 0; ch < 8; ++ch) {    // 8 chunks x 16 cols
    float h16[16];
    {
      const float4* bv = (const float4*)&b1s[ch * 16];
#pragma unroll
      for (int i = 0; i < 4; ++i) {
        float4 v = bv[i];  // broadcast
        h16[4 * i + 0] = v.x; h16[4 * i + 1] = v.y; h16[4 * i + 2] = v.z; h16[4 * i + 3] = v.w;
      }
    }
#pragma unroll
    for (int k = 0; k < INC; ++k) {
      const float4* wrow = (const float4*)&W1s[k * HID + ch * 16];
      float ak = a[k];
#pragma unroll
      for (int i = 0; i < 4; ++i) {
        float4 w = wrow[i];  // wave-uniform broadcast read
        h16[4 * i + 0] = fmaf(ak, w.x, h16[4 * i + 0]);
        h16[4 * i + 1] = fmaf(ak, w.y, h16[4 * i + 1]);
        h16[4 * i + 2] = fmaf(ak, w.z, h16[4 * i + 2]);
        h16[4 * i + 3] = fmaf(ak, w.w, h16[4 * i + 3]);
      }
    }
    // relu + logit accumulation (fully unrolled, constant indices)
#pragma unroll
    for (int i = 0; i < 16; ++i) {
      float hr = fmaxf(h16[i], 0.f);
      h16[i] = hr;
      const float4* wp = (const float4*)&Wps[(ch * 16 + i) * 12];
      float4 w0 = wp[0], w1 = wp[1], w2 = wp[2];  // broadcast
      logit[0] = fmaf(hr, w0.x, logit[0]);
      logit[1] = fmaf(hr, w0.y, logit[1]);
      logit[2] = fmaf(hr, w0.z, logit[2]);
      logit[3] = fmaf(hr, w0.w, logit[3]);
      logit[4] = fmaf(hr, w1.x, logit[4]);
      logit[5] = fmaf(hr, w1.y, logit[5]);
      logit[6] = fmaf(hr, w1.z, logit[6]);
      logit[7] = fmaf(hr, w1.w, logit[7]);
      logit[8] = fmaf(hr, w2.x, logit[8]);
    }
#pragma unroll
    for (int i = 0; i < 4; ++i)
      hout[ch * 4 + i] = make_float4(h16[4 * i], h16[4 * i + 1], h16[4 * i + 2], h16[4 * i + 3]);
  }

  // softmax (lane-local, no shuffles)
  float m = logit[0];
#pragma unroll
  for (int q = 1; q < KC; ++q) m = fmaxf(m, logit[q]);
  float Z = 0.f;
#pragma unroll
  for (int q = 0; q < KC; ++q) { logit[q] = __expf(logit[q] - m); Z += logit[q]; }
  float inv = 1.0f / Z;
#pragma unroll
  for (int q = 0; q < KC; ++q) logit[q] *= inv;

  float* so = s_out + (size_t)node * KC;
#pragma unroll
  for (int q = 0; q < KC; ++q) so[q] = logit[q];
  float4* sp = (float4*)(s_pad + (size_t)node * 12);
  sp[0] = make_float4(logit[0], logit[1], logit[2], logit[3]);
  sp[1] = make_float4(logit[4], logit[5], logit[6], logit[7]);
  sp[2] = make_float4(logit[8], 0.f, 0.f, 0.f);
}

// ---- pool B: column-ownership reductions. x_pool = S^T H, ss = S^T S, den.

__global__ __launch_bounds__(256) void k_poolB(const float* __restrict__ h_glob,
                                               const float* __restrict__ s_pad,
                                               const int* __restrict__ degi,
                                               float* __restrict__ glob) {
  int t = threadIdx.x;
  int wave = t >> 6, lane = t & 63;
  int gw = blockIdx.x * 4 + wave;
  int nw = gridDim.x * 4;
  const int c0 = 2 * lane;

  float pool0[KC], pool1[KC], ssr[KC];
  float den_acc = 0.f;
#pragma unroll
  for (int q = 0; q < KC; ++q) { pool0[q] = 0.f; pool1[q] = 0.f; ssr[q] = 0.f; }

  for (int node0 = gw; node0 < NN; node0 += nw) {
    int node = __builtin_amdgcn_readfirstlane(node0);
    float2 hv = *(const float2*)&h_glob[(size_t)node * HID + c0];  // coalesced
    const float* srow = s_pad + (size_t)node * 12;
    float4 s0 = *(const float4*)srow;
    float4 s1 = *(const float4*)(srow + 4);
    float s8 = srow[8];
    float sb[KC] = {s0.x, s0.y, s0.z, s0.w, s1.x, s1.y, s1.z, s1.w, s8};
    float sq = (lane < KC) ? srow[lane] : 0.f;
    float dg = (float)degi[node];

#pragma unroll
    for (int q = 0; q < KC; ++q) {
      pool0[q] = fmaf(sb[q], hv.x, pool0[q]);
      pool1[q] = fmaf(sb[q], hv.y, pool1[q]);
    }
    if (lane < KC) {
#pragma unroll
      for (int q = 0; q < KC; ++q) ssr[q] = fmaf(sq, sb[q], ssr[q]);
      den_acc = fmaf(dg * sq, sq, den_acc);
    }
  }

  __shared__ float pool_sh[KC * HID + 82];
  float* ss_sh = pool_sh + KC * HID;
  float* den_sh = ss_sh + 81;
  for (int i = t; i < KC * HID + 82; i += 256) pool_sh[i] = 0.f;
  __syncthreads();

#pragma unroll
  for (int q = 0; q < KC; ++q) {
    atomicAdd(&pool_sh[q * HID + c0], pool0[q]);
    atomicAdd(&pool_sh[q * HID + c0 + 1], pool1[q]);
  }
  if (lane < KC) {
#pragma unroll
    for (int q = 0; q < KC; ++q) atomicAdd(&ss_sh[lane * KC + q], ssr[q]);
    atomicAdd(den_sh, den_acc);
  }
  __syncthreads();

  for (int i = t; i < KC * HID; i += 256) atomAddG(&glob[G_XP + i], pool_sh[i]);
  if (t < KC * KC) atomAddG(&glob[G_SS + t], ss_sh[t]);
  if (t == 0) atomAddG(&glob[G_DEN], *den_sh);
}

// ---- out_adj via CSR: g[dst] = sum_{src in N(dst)} s[src]; OA = sum g(x)s[dst]

__global__ __launch_bounds__(256) void k_adj(const int* __restrict__ rowptr, const int* __restrict__ degi,
                                             const int* __restrict__ csr, const float* __restrict__ s_pad,
                                             float* __restrict__ oa_g) {
  int t = threadIdx.x;
  int tid = blockIdx.x * blockDim.x + t;
  int stride = gridDim.x * blockDim.x;

  float acc[81];
#pragma unroll
  for (int i = 0; i < 81; ++i) acc[i] = 0.f;

  for (int node = tid; node < NN; node += stride) {
    int base = rowptr[node];
    int cnt = degi[node];
    float4 g0 = make_float4(0.f, 0.f, 0.f, 0.f);
    float4 g1 = g0;
    float g8 = 0.f;
    int j = 0;
    for (; j + 1 < cnt; j += 2) {
      int s0 = csr[base + j], s1 = csr[base + j + 1];
      const float4* p0 = (const float4*)(s_pad + (size_t)s0 * 12);
      const float4* p1 = (const float4*)(s_pad + (size_t)s1 * 12);
      float4 a0 = p0[0], b0 = p0[1], c0 = p0[2];
      float4 a1 = p1[0], b1 = p1[1], c1 = p1[2];
      g0.x += a0.x + a1.x; g0.y += a0.y + a1.y; g0.z += a0.z + a1.z; g0.w += a0.w + a1.w;
      g1.x += b0.x + b1.x; g1.y += b0.y + b1.y; g1.z += b0.z + b1.z; g1.w += b0.w + b1.w;
      g8 += c0.x + c1.x;
    }
    if (j < cnt) {
      int s0 = csr[base + j];
      const float4* p0 = (const float4*)(s_pad + (size_t)s0 * 12);
      float4 a0 = p0[0], b0 = p0[1], c0 = p0[2];
      g0.x += a0.x; g0.y += a0.y; g0.z += a0.z; g0.w += a0.w;
      g1.x += b0.x; g1.y += b0.y; g1.z += b0.z; g1.w += b0.w;
      g8 += c0.x;
    }
    const float4* sn = (const float4*)(s_pad + (size_t)node * 12);
    float4 d0 = sn[0], d1 = sn[1], d2 = sn[2];
    float gg[9] = {g0.x, g0.y, g0.z, g0.w, g1.x, g1.y, g1.z, g1.w, g8};
    float sd[9] = {d0.x, d0.y, d0.z, d0.w, d1.x, d1.y, d1.z, d1.w, d2.x};
#pragma unroll
    for (int i = 0; i < 9; ++i)
#pragma unroll
      for (int jj = 0; jj < 9; ++jj) acc[i * 9 + jj] = fmaf(gg[i], sd[jj], acc[i * 9 + jj]);
  }

  __shared__ float wsum[4][81];
#pragma unroll
  for (int i = 0; i < 81; ++i) {
#pragma unroll
    for (int off = 32; off > 0; off >>= 1) acc[i] += __shfl_xor(acc[i], off, 64);
  }
  int wave = t >> 6, lane = t & 63;
  if (lane == 0) {
#pragma unroll
    for (int i = 0; i < 81; ++i) wsum[wave][i] = acc[i];
  }
  __syncthreads();
  if (t < 81) atomAddG(&oa_g[t], wsum[0][t] + wsum[1][t] + wsum[2][t] + wsum[3][t]);
}

// ---- epilogue ----------------------------------------------------------

__global__ __launch_bounds__(128) void k_final(const float* __restrict__ glob, float* __restrict__ out) {
  const float* xp = glob + G_XP;
  const float* oa = glob + G_OA;
  const float* ssm = glob + G_SS;
  const float* den = glob + G_DEN;
  int t = threadIdx.x;
  __shared__ float red[128];

  for (int k = 0; k < 9; ++k) {
    float v = xp[k * 128 + t];
    red[t] = v;
    __syncthreads();
    for (int s2 = 64; s2 > 0; s2 >>= 1) {
      if (t < s2) red[t] = fmaxf(red[t], red[t + s2]);
      __syncthreads();
    }
    float m = red[0];
    __syncthreads();
    red[t] = expf(v - m);
    __syncthreads();
    for (int s2 = 64; s2 > 0; s2 >>= 1) {
      if (t < s2) red[t] += red[t + s2];
      __syncthreads();
    }
    float lz = logf(red[0]) + m;
    __syncthreads();
    out[k * 128 + t] = v - lz;
  }

  if (t == 0) {
    float num = 0.f;
    for (int q = 0; q < 9; ++q) num += oa[q * 9 + q];
    out[1152] = -(num / (den[0] + 1e-15f));

    float fn = 0.f;
    for (int i = 0; i < 81; ++i) fn += ssm[i] * ssm[i];
    float rfn = 1.0f / sqrtf(fn);
    float osum = 0.f;
    for (int i = 0; i < 9; ++i)
      for (int j = 0; j < 9; ++j) {
        float v = ssm[i * 9 + j] * rfn - ((i == j) ? (1.0f / 3.0f) : 0.f);
        osum += v * v;
      }
    out[1153] = sqrtf(osum);
  }

  __shared__ float dsh[9];
  if (t < 9) {
    float d = 0.f;
    for (int j = 0; j < 9; ++j)
      if (j != t) d += oa[t * 9 + j];
    dsh[t] = 1.0f / sqrtf(d + 1e-15f);
  }
  __syncthreads();
  if (t < 81) {
    int i = t / 9, j = t % 9;
    out[901154 + t] = (i == j) ? 0.f : dsh[i] * oa[t] * dsh[j];
  }
}

extern "C" void kernel_launch(void* const* d_in, const int* in_sizes, int n_in,
                              void* d_out, int out_size, void* d_ws, size_t ws_size,
                              hipStream_t stream) {
  const float* x = (const float*)d_in[0];
  const int* ei = (const int*)d_in[1];
  const float* W1 = (const float*)d_in[3];
  const float* b1 = (const float*)d_in[4];
  const float* Wp = (const float*)d_in[5];
  const float* bp = (const float*)d_in[6];
  float* out = (float*)d_out;

  // ws: deg_i[NN] | glob[1315] | rowptr[NN] | cursor[NN] | csr[NE] | dinv[NN] |
  //     s_pad[NN*12] | bsum[NB] | boff[NB] | agg[NN*64] | h_glob[NN*128]
  int* deg_i = (int*)d_ws;
  float* glob = (float*)d_ws + NN;
  int* rowptr = (int*)d_ws + NN + 1315;
  int* cursor = rowptr + NN;
  int* csr = cursor + NN;
  float* dinv = (float*)(csr + NE);
  float* s_pad = dinv + NN;
  int* bsum = (int*)(s_pad + (size_t)NN * 12);
  int* boff = bsum + NB;
  float* agg = (float*)(boff + NB);
  float* h_glob = agg + (size_t)NN * INC;

  hipMemsetAsync(d_ws, 0, (size_t)(NN + 1315) * sizeof(float), stream);

  const int* src = ei;
  const int* dst = ei + NE;

  hipLaunchKernelGGL(k_deg, dim3(1024), dim3(256), 0, stream, dst, deg_i);
  hipLaunchKernelGGL(k_bsum, dim3(NB), dim3(256), 0, stream, deg_i, bsum);
  hipLaunchKernelGGL(k_scanb, dim3(1), dim3(128), 0, stream, bsum, boff);
  hipLaunchKernelGGL(k_write, dim3(NB), dim3(256), 0, stream, deg_i, boff, rowptr, cursor, dinv);
  hipLaunchKernelGGL(k_fill, dim3(1024), dim3(256), 0, stream, src, dst, cursor, csr);
  hipLaunchKernelGGL(k_gather, dim3(6250), dim3(256), 0, stream, rowptr, deg_i, csr, x, dinv, agg);
  hipLaunchKernelGGL(k_mlpA, dim3((NN + 255) / 256), dim3(256), 0, stream, agg,
                     W1, b1, Wp, bp, out + 1154, s_pad, h_glob);
  hipLaunchKernelGGL(k_poolB, dim3(512), dim3(256), 0, stream, h_glob, s_pad, deg_i, glob);
  hipLaunchKernelGGL(k_adj, dim3(512), dim3(256), 0, stream, rowptr, deg_i, csr, s_pad, glob + G_OA);
  hipLaunchKernelGGL(k_final, dim3(1), dim3(128), 0, stream, glob, out);
}